// Round 6
// baseline (269.773 us; speedup 1.0000x reference)
//
#include <hip/hip_runtime.h>
#include <hip/hip_bf16.h>

#define NB 16
#define NW 64
#define NV 64
#define ND 256
#define NR 64
#define NN 4096
#define NEGV -10000000000.0f

typedef __attribute__((ext_vector_type(8))) short short8;
typedef __attribute__((ext_vector_type(4))) float f32x4;

__device__ inline float cvt(const void* p, int idx, int flag) {
  if (flag) return __bfloat162float(((const __hip_bfloat16*)p)[idx]);
  return ((const float*)p)[idx];
}
__device__ inline void stv(void* p, int idx, float v, int flag) {
  if (flag) ((__hip_bfloat16*)p)[idx] = __float2bfloat16(v);
  else ((float*)p)[idx] = v;
}
__device__ inline float bf2f(short s) {
  return __uint_as_float(((unsigned int)(unsigned short)s) << 16);
}
__device__ inline float tanh_fast(float x) {
  float ax = fabsf(x);
  float e = __expf(-2.f * ax);
  float r = (1.f - e) / (1.f + e);
  return copysignf(r, x);
}

// ---------- K0: detect input dtype (bf16 vs f32) ----------
__global__ void k_detect(const unsigned int* embw, int* flagp) {
  __shared__ float red[256];
  int t = threadIdx.x;
  float mx = 0.f;
  for (int i = t; i < 1024; i += 256) {
    unsigned int w = embw[i];
    unsigned int fb = (w & 0xffffu) << 16;
    float a = fabsf(__uint_as_float(fb));
    if (!(a < 1e9f)) a = 1e9f;
    mx = fmaxf(mx, a);
  }
  red[t] = mx;
  __syncthreads();
  for (int s = 128; s > 0; s >>= 1) {
    if (t < s) red[t] = fmaxf(red[t], red[t + s]);
    __syncthreads();
  }
  if (t == 0) flagp[0] = (red[0] < 1000.f) ? 1 : 0;
}

// ---------- K1 (merged prep): relaT | small params | w1 pack | gather ----------
__global__ void k_prep(const void* rela, float* relaT,
                       const void* b1, const void* w2, const void* outw,
                       const void* b2, const void* outb, float* sp,
                       const void* w1, __hip_bfloat16* w1b,
                       const int* head, const int* tail, const void* emb,
                       float* Af, float* Bf, const int* flagp) {
  int flag = flagp[0];
  int blk = blockIdx.x;
  int t = threadIdx.x;
  if (blk < 64) {
    relaT[t * NR + blk] = cvt(rela, blk * ND + t, flag);
  } else if (blk == 64) {
    sp[t] = cvt(b1, t, flag);
    sp[256 + t] = cvt(w2, t, flag);
    sp[512 + t] = cvt(outw, t, flag);
    if (t == 0) {
      sp[768] = cvt(b2, 0, flag);
      sp[769] = cvt(outb, 0, flag);
    }
  } else if (blk < 321) {
    int flat = (blk - 65) * 256 + t;  // 65536
    int i = flat & 7;
    int lane = (flat >> 3) & 63;
    int kst = (flat >> 9) & 7;
    int nt = flat >> 12;
    int k = kst * 32 + (lane >> 4) * 8 + i;
    int n = nt * 16 + (lane & 15);
    w1b[flat] = __float2bfloat16(cvt(w1, k * ND + n, flag));
  } else {
    int row = blk - 321;  // 0..2047
    if (row < NB * NW) {
      int ix = head[row];
      Af[row * ND + t] = cvt(emb, ix * ND + t, flag);
    } else {
      int rr = row - NB * NW;
      int ix = tail[rr];
      Bf[rr * ND + t] = cvt(emb, ix * ND + t, flag);
    }
  }
}

// ---------- K3: Ah = A@Wa + fc_b, Bh = B@Wb, RWb = pack(rela@Wc) ----------
__global__ void __launch_bounds__(256) k_premm(const float* Af, const float* Bf,
                                               const void* rela, const void* fcw,
                                               const void* fcb, float* Ah,
                                               float* Bh, __hip_bfloat16* rwb,
                                               const int* flagp) {
  int flag = flagp[0];
  int blk = blockIdx.x;
  int t = threadIdx.x;
  __shared__ float rl[4][ND];
  int base, wbase, addb = 0, isr = 0;
  const float* src = Af;
  if (blk < 256) { base = blk * 4; wbase = 0; addb = 1; }
  else if (blk < 512) { base = (blk - 256) * 4; src = Bf; wbase = ND; }
  else { base = (blk - 512) * 4; wbase = 2 * ND; isr = 1; }
#pragma unroll
  for (int i = 0; i < 4; ++i)
    rl[i][t] = isr ? cvt(rela, (base + i) * ND + t, flag)
                   : src[(base + i) * ND + t];
  __syncthreads();
  float acc0 = 0.f, acc1 = 0.f, acc2 = 0.f, acc3 = 0.f;
  const f32x4* r0p = (const f32x4*)rl[0];
  const f32x4* r1p = (const f32x4*)rl[1];
  const f32x4* r2p = (const f32x4*)rl[2];
  const f32x4* r3p = (const f32x4*)rl[3];
  for (int k4 = 0; k4 < 64; ++k4) {
    float w0 = cvt(fcw, (wbase + k4 * 4 + 0) * ND + t, flag);
    float w1v = cvt(fcw, (wbase + k4 * 4 + 1) * ND + t, flag);
    float w2v = cvt(fcw, (wbase + k4 * 4 + 2) * ND + t, flag);
    float w3v = cvt(fcw, (wbase + k4 * 4 + 3) * ND + t, flag);
    f32x4 r0 = r0p[k4], r1 = r1p[k4], r2 = r2p[k4], r3 = r3p[k4];
    acc0 += r0.x * w0 + r0.y * w1v + r0.z * w2v + r0.w * w3v;
    acc1 += r1.x * w0 + r1.y * w1v + r1.z * w2v + r1.w * w3v;
    acc2 += r2.x * w0 + r2.y * w1v + r2.z * w2v + r2.w * w3v;
    acc3 += r3.x * w0 + r3.y * w1v + r3.z * w2v + r3.w * w3v;
  }
  float bias = addb ? cvt(fcb, t, flag) : 0.f;
  float res[4] = {acc0 + bias, acc1 + bias, acc2 + bias, acc3 + bias};
  if (!isr) {
    float* dst = addb ? Ah : Bh;
#pragma unroll
    for (int i = 0; i < 4; ++i) dst[(base + i) * ND + t] = res[i];
  } else {
#pragma unroll
    for (int i = 0; i < 4; ++i) {
      int rr = base + i;
      int ks = rr >> 5, ii = rr & 7, lh = (rr >> 3) & 3;
      int nt = t >> 4, ll = t & 15;
      int flat = ((nt * 2 + ks) * 64 + lh * 16 + ll) * 8 + ii;
      rwb[flat] = __float2bfloat16(res[i]);
    }
  }
}

// ---------- K4: scores -> mask -> softmax -> norm_scores ----------
// j-split x4: blk = bi*4 + js, each block does 16 j's (4 groups of 4).
// Per-(b,i,j) FP op order is bit-identical to R3/R5 — required because the
// s<=null mask is a knife-edge f32 comparison.
__global__ void __launch_bounds__(256) k_scores(const float* Af, const float* Bf,
                                                const float* relaT, void* out,
                                                __hip_bfloat16* nsb,
                                                const int* flagp) {
  int flag = flagp[0];
  int blk = blockIdx.x;        // 4096
  int bi = blk >> 2;           // b*64 + i
  int js = blk & 3;            // j-split index
  int b = bi >> 6;
  int t = threadIdx.x;         // 256
  int r = t & 63;
  int q = t >> 6;
  __shared__ float Al[ND];
  __shared__ float Bl[4 * ND];
  __shared__ float part[4 * 256];
  Al[t] = Af[bi * ND + t];
  __syncthreads();
  float preR[64];
#pragma unroll
  for (int i2 = 0; i2 < 64; ++i2) {
    int d = q * 64 + i2;
    preR[i2] = Al[d] * relaT[d * NR + r];
  }
  const f32x4* Bl4 = (const f32x4*)Bl;
  for (int jg = js * 4; jg < js * 4 + 4; ++jg) {
#pragma unroll
    for (int jj = 0; jj < 4; ++jj)
      Bl[jj * ND + t] = Bf[(b * NV + jg * 4 + jj) * ND + t];
    __syncthreads();
#pragma unroll
    for (int jj = 0; jj < 4; ++jj) {
      float acc = 0.f;
      int ib = jj * 64 + q * 16;
#pragma unroll
      for (int i4 = 0; i4 < 16; ++i4) {
        f32x4 bv = Bl4[ib + i4];
        acc += preR[i4 * 4 + 0] * bv.x;
        acc += preR[i4 * 4 + 1] * bv.y;
        acc += preR[i4 * 4 + 2] * bv.z;
        acc += preR[i4 * 4 + 3] * bv.w;
      }
      part[jj * 256 + t] = acc;
    }
    __syncthreads();
    {
      int j4 = q;   // this wave's j
      float s = part[j4 * 256 + r] + part[j4 * 256 + 64 + r]
              + part[j4 * 256 + 128 + r] + part[j4 * 256 + 192 + r];
      float nullv = __shfl(s, 63, 64);
      float m = (s <= nullv) ? NEGV : s;
      float mx = m;
#pragma unroll
      for (int o = 32; o > 0; o >>= 1) mx = fmaxf(mx, __shfl_xor(mx, o, 64));
      float e = __expf(m - mx);
      float sum = e;
#pragma unroll
      for (int o = 32; o > 0; o >>= 1) sum += __shfl_xor(sum, o, 64);
      float ns = e / sum;
      int j = jg * 4 + j4;
      int nidx = (bi * 64 + j) * 64 + r;
      stv(out, 16 + NB * NN + nidx, ns, flag);
      nsb[nidx] = __float2bfloat16(ns);
    }
    __syncthreads();
  }
}

// ---------- K5 (MFMA): tuple = tanh(NS@RW + Ah + Bh) -> bf16 ----------
__global__ void __launch_bounds__(256) k_tuple2(const __hip_bfloat16* nsb,
                                                const __hip_bfloat16* rwb,
                                                const float* Ah, const float* Bh,
                                                __hip_bfloat16* tup) {
  int t = threadIdx.x;
  int wv = t >> 6, lane = t & 63;
  int bi = blockIdx.x;       // 1024
  int b = bi >> 6;
  const short* nsS = (const short*)nsb;
  const short* rwS = (const short*)rwb;
  int m = lane & 15;
  int kgrp = lane >> 4;
  f32x4 acc[16];
#pragma unroll
  for (int i = 0; i < 16; ++i) acc[i] = (f32x4){0.f, 0.f, 0.f, 0.f};
  int nrow = bi * 64 + wv * 16 + m;
#pragma unroll
  for (int ks = 0; ks < 2; ++ks) {
    short8 a = *(const short8*)(nsS + (size_t)nrow * 64 + ks * 32 + kgrp * 8);
#pragma unroll
    for (int nt = 0; nt < 16; ++nt) {
      short8 bfr = *(const short8*)(rwS + (((nt * 2 + ks) * 64 + lane) << 3));
      acc[nt] = __builtin_amdgcn_mfma_f32_16x16x32_bf16(a, bfr, acc[nt], 0, 0, 0);
    }
  }
  int rbase = bi * 64 + wv * 16 + (lane >> 4) * 4;
  int jbase = rbase & 63;
#pragma unroll
  for (int nt = 0; nt < 16; ++nt) {
    int col = nt * 16 + m;
    float ahv = Ah[bi * ND + col];
#pragma unroll
    for (int reg = 0; reg < 4; ++reg) {
      int ng = rbase + reg;
      float v = acc[nt][reg] + ahv + Bh[(size_t)(b * 64 + jbase + reg) * ND + col];
      tup[(size_t)ng * ND + col] = __float2bfloat16(tanh_fast(v));
    }
  }
}

// ---------- K6 (MFMA): att_raw = tanh(T@W1+b1)@w2+b2 ; dotv = T@out_w ----------
__global__ void __launch_bounds__(256) k_att2(const __hip_bfloat16* tup,
                                              const __hip_bfloat16* w1b,
                                              const float* sp,
                                              float* att_raw, float* dotv) {
  int t = threadIdx.x;
  int wv = t >> 6, lane = t & 63;
  int r0 = blockIdx.x * 128 + wv * 32;
  const short* tupS = (const short*)tup;
  const short* w1S = (const short*)w1b;
  const float* owf = sp + 512;
  float b2v = sp[768];

  f32x4 acc0[16], acc1[16];
#pragma unroll
  for (int i = 0; i < 16; ++i) {
    acc0[i] = (f32x4){0.f, 0.f, 0.f, 0.f};
    acc1[i] = (f32x4){0.f, 0.f, 0.f, 0.f};
  }
  float dp0 = 0.f, dp1 = 0.f;
  int arow0 = r0 + (lane & 15);
  int arow1 = arow0 + 16;
  int kgrp = lane >> 4;

#pragma unroll
  for (int ks = 0; ks < 8; ++ks) {
    int k0 = ks * 32 + kgrp * 8;
    short8 a0 = *(const short8*)(tupS + (size_t)arow0 * ND + k0);
    short8 a1 = *(const short8*)(tupS + (size_t)arow1 * ND + k0);
#pragma unroll
    for (int i = 0; i < 8; ++i) {
      float w = owf[k0 + i];
      dp0 += bf2f(a0[i]) * w;
      dp1 += bf2f(a1[i]) * w;
    }
#pragma unroll
    for (int nt = 0; nt < 16; ++nt) {
      short8 bfr = *(const short8*)(w1S + (((nt * 8 + ks) * 64 + lane) << 3));
      acc0[nt] = __builtin_amdgcn_mfma_f32_16x16x32_bf16(a0, bfr, acc0[nt], 0, 0, 0);
      acc1[nt] = __builtin_amdgcn_mfma_f32_16x16x32_bf16(a1, bfr, acc1[nt], 0, 0, 0);
    }
  }

  dp0 += __shfl_xor(dp0, 16, 64); dp0 += __shfl_xor(dp0, 32, 64);
  dp1 += __shfl_xor(dp1, 16, 64); dp1 += __shfl_xor(dp1, 32, 64);
  if (lane < 16) {
    dotv[r0 + lane] = dp0;
    dotv[r0 + 16 + lane] = dp1;
  }

  float p0[4] = {0.f, 0.f, 0.f, 0.f};
  float p1[4] = {0.f, 0.f, 0.f, 0.f};
#pragma unroll
  for (int nt = 0; nt < 16; ++nt) {
    int col = nt * 16 + (lane & 15);
    float b1v = sp[col];
    float w2v = sp[256 + col];
#pragma unroll
    for (int reg = 0; reg < 4; ++reg) {
      p0[reg] += tanh_fast(acc0[nt][reg] + b1v) * w2v;
      p1[reg] += tanh_fast(acc1[nt][reg] + b1v) * w2v;
    }
  }
#pragma unroll
  for (int o = 1; o < 16; o <<= 1) {
#pragma unroll
    for (int reg = 0; reg < 4; ++reg) {
      p0[reg] += __shfl_xor(p0[reg], o, 64);
      p1[reg] += __shfl_xor(p1[reg], o, 64);
    }
  }
  if ((lane & 15) == 0) {
    int rb = r0 + (lane >> 4) * 4;
#pragma unroll
    for (int reg = 0; reg < 4; ++reg) {
      att_raw[rb + reg] = p0[reg] + b2v;
      att_raw[rb + 16 + reg] = p1[reg] + b2v;
    }
  }
}

// ---------- K7: att softmax over N -> att_norms out; logits ----------
__global__ void k_fuse(const float* att_raw, const float* dotv,
                       const float* sp, void* out, const int* flagp) {
  int flag = flagp[0];
  int b = blockIdx.x;
  int t = threadIdx.x;
  __shared__ float red[256];
  float vals[16];
  float mx = -3.4e38f;
#pragma unroll
  for (int c = 0; c < 16; ++c) {
    vals[c] = att_raw[b * NN + c * 256 + t];
    mx = fmaxf(mx, vals[c]);
  }
  red[t] = mx;
  __syncthreads();
  for (int s = 128; s > 0; s >>= 1) {
    if (t < s) red[t] = fmaxf(red[t], red[t + s]);
    __syncthreads();
  }
  float M = red[0];
  __syncthreads();
  float sm = 0.f;
#pragma unroll
  for (int c = 0; c < 16; ++c) {
    vals[c] = __expf(vals[c] - M);
    sm += vals[c];
  }
  red[t] = sm;
  __syncthreads();
  for (int s = 128; s > 0; s >>= 1) {
    if (t < s) red[t] += red[t + s];
    __syncthreads();
  }
  float Z = red[0];
  __syncthreads();
  float acc = 0.f;
#pragma unroll
  for (int c = 0; c < 16; ++c) {
    int n = c * 256 + t;
    float a = vals[c] / Z;
    stv(out, 16 + b * NN + n, a, flag);
    acc += a * dotv[b * NN + n];
  }
  red[t] = acc;
  __syncthreads();
  for (int s = 128; s > 0; s >>= 1) {
    if (t < s) red[t] += red[t + s];
    __syncthreads();
  }
  if (t == 0) stv(out, b, red[0] + sp[769], flag);   // + out_b
}

// ---------- host ----------
extern "C" void kernel_launch(void* const* d_in, const int* in_sizes, int n_in,
                              void* d_out, int out_size, void* d_ws, size_t ws_size,
                              hipStream_t stream) {
  const int* head = (const int*)d_in[0];
  const int* tail = (const int*)d_in[1];
  const void* emb = d_in[2];
  const void* rela = d_in[3];
  const void* fcw = d_in[4];
  const void* fcb = d_in[5];
  const void* w1 = d_in[6];
  const void* b1 = d_in[7];
  const void* w2 = d_in[8];
  const void* b2 = d_in[9];
  const void* outw = d_in[10];
  const void* outb = d_in[11];

  float* ws = (float*)d_ws;
  int* flagp = (int*)d_ws;
  const size_t O_RELAT = 16;
  const size_t O_AF = O_RELAT + 16384;
  const size_t O_BF = O_AF + 262144;
  const size_t O_AH = O_BF + 262144;
  const size_t O_BH = O_AH + 262144;
  const size_t O_ATTR = O_BH + 262144;
  const size_t O_DOT = O_ATTR + 65536;
  const size_t O_SP = O_DOT + 65536;
  const size_t O_W1B = O_SP + 1024;        // 65536 bf16
  const size_t O_RWB = O_W1B + 32768;      // 16384 bf16
  const size_t O_NSB = O_RWB + 8192;       // 4.19M bf16
  const size_t O_TUP = O_NSB + 2097152;    // 16.8M bf16

  float* relaT = ws + O_RELAT;
  float* Af = ws + O_AF;
  float* Bf = ws + O_BF;
  float* Ah = ws + O_AH;
  float* Bh = ws + O_BH;
  float* attr = ws + O_ATTR;
  float* dotv = ws + O_DOT;
  float* sp = ws + O_SP;
  __hip_bfloat16* w1b = (__hip_bfloat16*)(ws + O_W1B);
  __hip_bfloat16* rwb = (__hip_bfloat16*)(ws + O_RWB);
  __hip_bfloat16* nsb = (__hip_bfloat16*)(ws + O_NSB);
  __hip_bfloat16* tup = (__hip_bfloat16*)(ws + O_TUP);

  hipLaunchKernelGGL(k_detect, dim3(1), dim3(256), 0, stream,
                     (const unsigned int*)emb, flagp);
  hipLaunchKernelGGL(k_prep, dim3(2369), dim3(256), 0, stream,
                     rela, relaT, b1, w2, outw, b2, outb, sp,
                     w1, w1b, head, tail, emb, Af, Bf, flagp);
  hipLaunchKernelGGL(k_premm, dim3(528), dim3(256), 0, stream,
                     Af, Bf, rela, fcw, fcb, Ah, Bh, rwb, flagp);
  hipLaunchKernelGGL(k_scores, dim3(4096), dim3(256), 0, stream,
                     Af, Bf, relaT, d_out, nsb, flagp);
  hipLaunchKernelGGL(k_tuple2, dim3(1024), dim3(256), 0, stream,
                     nsb, rwb, Ah, Bh, tup);
  hipLaunchKernelGGL(k_att2, dim3(512), dim3(256), 0, stream,
                     tup, w1b, sp, attr, dotv);
  hipLaunchKernelGGL(k_fuse, dim3(16), dim3(256), 0, stream,
                     attr, dotv, sp, d_out, flagp);
}